// Round 1
// baseline (437.837 us; speedup 1.0000x reference)
//
#include <hip/hip_runtime.h>
#include <math.h>

#define NN 10000       // N_NODES
#define NE 160000      // N_EDGES
#define NG 100         // N_GRAPHS
#define DD 32
#define QQ 96
#define EPS 1e-5f

// ---------------------------------------------------------------- graph ranges
__global__ void k_gstart(const int* __restrict__ batch, int* __restrict__ start) {
    int b = threadIdx.x;
    if (b > NG) return;
    int lo = 0, hi = NN;
    while (lo < hi) { int mid = (lo + hi) >> 1; if (batch[mid] < b) lo = mid + 1; else hi = mid; }
    start[b] = lo;
}

// ------------------------------------------------- edge-MLP column stats (BN)
__global__ __launch_bounds__(256) void k_stats(const float* __restrict__ ea,
        const float* __restrict__ nw, const float* __restrict__ nb,
        float* __restrict__ csum, float* __restrict__ csumsq) {
    __shared__ float lds_ea[128 * 6];
    const int tid = threadIdx.x;
    const int j0 = tid * 4;
    float w[4][6], bb[4];
#pragma unroll
    for (int c = 0; c < 4; ++c) {
#pragma unroll
        for (int k = 0; k < 6; ++k) w[c][k] = nw[(j0 + c) * 6 + k];
        bb[c] = nb[j0 + c];
    }
    float s[4] = {0, 0, 0, 0}, ss[4] = {0, 0, 0, 0};
    const int nchunk = NE / 128;
    for (int ch = blockIdx.x; ch < nchunk; ch += gridDim.x) {
        __syncthreads();
#pragma unroll
        for (int r = 0; r < 3; ++r) lds_ea[tid + 256 * r] = ea[ch * 768 + tid + 256 * r];
        __syncthreads();
        for (int el = 0; el < 128; ++el) {
            const float* e6 = &lds_ea[el * 6];
            float e0 = e6[0], e1 = e6[1], e2 = e6[2], e3 = e6[3], e4 = e6[4], e5 = e6[5];
#pragma unroll
            for (int c = 0; c < 4; ++c) {
                float y = bb[c];
                y = fmaf(e0, w[c][0], y); y = fmaf(e1, w[c][1], y); y = fmaf(e2, w[c][2], y);
                y = fmaf(e3, w[c][3], y); y = fmaf(e4, w[c][4], y); y = fmaf(e5, w[c][5], y);
                float r = fmaxf(y, 0.f);
                s[c] += r; ss[c] = fmaf(r, r, ss[c]);
            }
        }
    }
#pragma unroll
    for (int c = 0; c < 4; ++c) {
        atomicAdd(&csum[j0 + c], s[c]);
        atomicAdd(&csumsq[j0 + c], ss[c]);
    }
}

// ------------------------------------------------------- BN -> affine (A, B)
__global__ void k_finalize(const float* __restrict__ csum, const float* __restrict__ csumsq,
        const float* __restrict__ g, const float* __restrict__ beta,
        float* __restrict__ A, float* __restrict__ B, int n, float invE) {
    int j = blockIdx.x * blockDim.x + threadIdx.x;
    if (j >= n) return;
    float mean = csum[j] * invE;
    float var = fmaxf(csumsq[j] * invE - mean * mean, 0.f);
    float inv = rsqrtf(var + EPS);
    float a = g[j] * inv;
    A[j] = a;
    B[j] = beta[j] - mean * a;
}

// -------------------------------------------- out[n,o] = bias[o] + x[n]@root
__global__ __launch_bounds__(256) void k_root(const float* __restrict__ x,
        const float* __restrict__ root, const float* __restrict__ bias,
        float* __restrict__ out) {
    __shared__ float rlds[1024];
    const int tid = threadIdx.x;
#pragma unroll
    for (int r = 0; r < 4; ++r) rlds[tid + 256 * r] = root[tid + 256 * r];
    __syncthreads();
    const int o = tid & 31;
    const int gg = tid >> 5;
    const int n = blockIdx.x * 8 + gg;
    if (n >= NN) return;
    const int half = tid & 32;
    float xs = x[n * 32 + o];
    float acc = bias[o];
#pragma unroll
    for (int i = 0; i < 32; ++i) {
        float xi = __shfl(xs, half | i);
        acc = fmaf(xi, rlds[i * 32 + o], acc);
    }
    out[n * 32 + o] = acc;
}

// --------------------- fused edge-MLP recompute + matvec + scatter-add (NNConv)
__global__ __launch_bounds__(256) void k_conv(const float* __restrict__ xin,
        const float* __restrict__ ea, const int* __restrict__ src, const int* __restrict__ dst,
        const float* __restrict__ nw, const float* __restrict__ nb,
        const float* __restrict__ A, const float* __restrict__ B,
        float* __restrict__ agg) {
    __shared__ float wT[8][1024];   // w0..w5, bias, A  (transposed: stride-1 -> no bank conflict)
    __shared__ float BB[1024];
    __shared__ float ea_s[64 * 6];
    __shared__ int src_s[64];
    __shared__ int dst_s[64];
    const int tid = threadIdx.x;
    for (int idx = tid; idx < 9216; idx += 256) {
        int k = idx >> 10, j = idx & 1023;
        float v;
        if (k < 6) v = nw[j * 6 + k];
        else if (k == 6) v = nb[j];
        else if (k == 7) v = A[j];
        else v = B[j];
        if (k < 8) wT[k][j] = v; else BB[j] = v;
    }
    const int o = tid & 31;
    const int hw = tid >> 5;       // 0..7 half-waves
    const int half = tid & 32;
    const int nchunk = NE / 64;
    for (int ch = blockIdx.x; ch < nchunk; ch += gridDim.x) {
        const int base = ch * 64;
        __syncthreads();  // protect LDS (also covers initial weight load)
        if (tid < 64) { src_s[tid] = src[base + tid]; dst_s[tid] = dst[base + tid]; }
        for (int idx = tid; idx < 384; idx += 256) ea_s[idx] = ea[base * 6 + idx];
        __syncthreads();
        float ear[8][6], xs[8], msg[8];
#pragma unroll
        for (int m = 0; m < 8; ++m) {
            const float* p = &ea_s[(hw * 8 + m) * 6];
#pragma unroll
            for (int k = 0; k < 6; ++k) ear[m][k] = p[k];
            xs[m] = xin[src_s[hw * 8 + m] * 32 + o];
            msg[m] = 0.f;
        }
#pragma unroll 4
        for (int i = 0; i < 32; ++i) {
            const int j = i * 32 + o;
            float w0 = wT[0][j], w1 = wT[1][j], w2 = wT[2][j];
            float w3 = wT[3][j], w4 = wT[4][j], w5 = wT[5][j];
            float bb = wT[6][j], aa = wT[7][j], bv = BB[j];
            const int sl = half | i;
#pragma unroll
            for (int m = 0; m < 8; ++m) {
                float xi = __shfl(xs[m], sl);
                float y = bb;
                y = fmaf(ear[m][0], w0, y); y = fmaf(ear[m][1], w1, y);
                y = fmaf(ear[m][2], w2, y); y = fmaf(ear[m][3], w3, y);
                y = fmaf(ear[m][4], w4, y); y = fmaf(ear[m][5], w5, y);
                float r = fmaxf(y, 0.f);
                float t = fmaf(aa, r, bv);
                msg[m] = fmaf(xi, t, msg[m]);
            }
        }
#pragma unroll
        for (int m = 0; m < 8; ++m)
            atomicAdd(&agg[dst_s[hw * 8 + m] * 32 + o], msg[m]);
    }
}

// ---------------------------------------- lin1: relu(cat(x1,x2)@W^T+b) + stats
__global__ __launch_bounds__(384) void k_lin1a(const float* __restrict__ x1,
        const float* __restrict__ x2, const float* __restrict__ lw, const float* __restrict__ lb,
        float* __restrict__ pre, float* __restrict__ gsum, float* __restrict__ gsumsq) {
    __shared__ float cat[4][64];
    __shared__ float sh_s[96], sh_ss[96];
    const int tid = threadIdx.x;
    const int np = tid / 96;   // 0..3
    const int q = tid - np * 96;
    float w[64];
#pragma unroll
    for (int k = 0; k < 64; ++k) w[k] = lw[q * 64 + k];
    const float bq = lb[q];
    float s = 0.f, ss = 0.f;
    for (int nb = blockIdx.x * 4; nb < NN; nb += gridDim.x * 4) {
        __syncthreads();
        if (tid < 256) {
            int n2 = tid >> 6, k = tid & 63;
            cat[n2][k] = (k < 32) ? x1[(nb + n2) * 32 + k] : x2[(nb + n2) * 32 + (k - 32)];
        }
        __syncthreads();
        float v = bq;
#pragma unroll
        for (int k = 0; k < 64; ++k) v = fmaf(cat[np][k], w[k], v);
        float r = fmaxf(v, 0.f);
        pre[(nb + np) * 96 + q] = r;
        s += r; ss = fmaf(r, r, ss);
    }
    __syncthreads();
    if (tid < 96) { sh_s[tid] = 0.f; sh_ss[tid] = 0.f; }
    __syncthreads();
    atomicAdd(&sh_s[q], s);
    atomicAdd(&sh_ss[q], ss);
    __syncthreads();
    if (tid < 96) {
        atomicAdd(&gsum[tid], sh_s[tid]);
        atomicAdd(&gsumsq[tid], sh_ss[tid]);
    }
}

__global__ __launch_bounds__(384) void k_lin1b(const float* __restrict__ gsum,
        const float* __restrict__ gsumsq, const float* __restrict__ g, const float* __restrict__ beta,
        const float* __restrict__ pre, float* __restrict__ xc) {
    const int tid = threadIdx.x;
    const int np = tid / 96;
    const int q = tid - np * 96;
    const float invN = 1.f / NN;
    float mean = gsum[q] * invN;
    float var = fmaxf(gsumsq[q] * invN - mean * mean, 0.f);
    float a = g[q] * rsqrtf(var + EPS);
    float b = beta[q] - mean * a;
    for (int nb = blockIdx.x * 4; nb < NN; nb += gridDim.x * 4) {
        int n = nb + np;
        xc[n * 96 + q] = fmaf(a, pre[n * 96 + q], b);
    }
}

// ------------------------------------------------- Set2Set: whole loop per graph
__global__ __launch_bounds__(256) void k_s2s(const float* __restrict__ xc,
        const int* __restrict__ start,
        const float* __restrict__ w_ih, const float* __restrict__ w_hh,
        const float* __restrict__ b_ih, const float* __restrict__ b_hh,
        float* __restrict__ qs_g, float* __restrict__ e_ws) {
    __shared__ float qs[192], h[96], c[96], gates[384], red[4];
    const int tid = threadIdx.x;
    const int b = blockIdx.x;
    const int s = start[b], t = start[b + 1];
    if (tid < 192) qs[tid] = 0.f;
    if (tid < 96) { h[tid] = 0.f; c[tid] = 0.f; }
    __syncthreads();
    for (int step = 0; step < 3; ++step) {
        // gates = qs@w_ih^T + b_ih + h@w_hh^T + b_hh
        for (int u = tid; u < 384; u += 256) {
            float acc = b_ih[u] + b_hh[u];
            const float* wi = &w_ih[u * 192];
#pragma unroll 8
            for (int k = 0; k < 192; ++k) acc = fmaf(qs[k], wi[k], acc);
            const float* wh = &w_hh[u * 96];
#pragma unroll 8
            for (int k = 0; k < 96; ++k) acc = fmaf(h[k], wh[k], acc);
            gates[u] = acc;
        }
        __syncthreads();
        if (tid < 96) {
            float ig = 1.f / (1.f + __expf(-gates[tid]));
            float fg = 1.f / (1.f + __expf(-gates[96 + tid]));
            float gg = tanhf(gates[192 + tid]);
            float og = 1.f / (1.f + __expf(-gates[288 + tid]));
            float cn = fg * c[tid] + ig * gg;
            c[tid] = cn;
            h[tid] = og * tanhf(cn);
        }
        __syncthreads();
        // attention logits + per-graph max
        float pmax = -INFINITY;
        for (int n = s + tid; n < t; n += 256) {
            const float* xr = &xc[n * 96];
            float acc = 0.f;
#pragma unroll 8
            for (int k = 0; k < 96; ++k) acc = fmaf(xr[k], h[k], acc);
            e_ws[n] = acc;
            pmax = fmaxf(pmax, acc);
        }
#pragma unroll
        for (int off = 32; off > 0; off >>= 1) pmax = fmaxf(pmax, __shfl_down(pmax, off));
        if ((tid & 63) == 0) red[tid >> 6] = pmax;
        __syncthreads();
        float emax = fmaxf(fmaxf(red[0], red[1]), fmaxf(red[2], red[3]));
        if (!isfinite(emax)) emax = 0.f;
        // softmax-weighted sum (divide at the end)
        float racc = 0.f, asum = 0.f;
        if (tid < 96) {
            for (int n = s; n < t; ++n) {
                float a = __expf(e_ws[n] - emax);
                racc = fmaf(a, xc[n * 96 + tid], racc);
                asum += a;
            }
        }
        __syncthreads();
        if (tid < 96) {
            float r = (asum > 0.f) ? racc / asum : 0.f;
            qs[tid] = h[tid];
            qs[96 + tid] = r;
        }
        __syncthreads();
    }
    if (tid < 192) qs_g[b * 192 + tid] = qs[tid];
}

// -------------------------------- xg = qs@s2s_w^T+b ; pre_m1 = relu(xg@m1^T+b)
__global__ __launch_bounds__(128) void k_xg(const float* __restrict__ qs_g,
        const float* __restrict__ sw, const float* __restrict__ sb,
        const float* __restrict__ m1w, const float* __restrict__ m1b,
        float* __restrict__ pre, float* __restrict__ gsum, float* __restrict__ gsumsq) {
    __shared__ float xg0[96];
    const int tid = threadIdx.x;
    const int b = blockIdx.x;
    if (tid < 96) {
        const float* q = &qs_g[b * 192];
        float acc = sb[tid];
        const float* w = &sw[tid * 192];
#pragma unroll 8
        for (int k = 0; k < 192; ++k) acc = fmaf(q[k], w[k], acc);
        xg0[tid] = acc;
    }
    __syncthreads();
    if (tid < 96) {
        float acc = m1b[tid];
        const float* w = &m1w[tid * 96];
#pragma unroll 8
        for (int k = 0; k < 96; ++k) acc = fmaf(xg0[k], w[k], acc);
        float r = fmaxf(acc, 0.f);
        pre[b * 96 + tid] = r;
        atomicAdd(&gsum[tid], r);
        atomicAdd(&gsumsq[tid], r * r);
    }
}

// ----------------------------------------- tail: BN(m1) -> m2 linear+relu+BN
__global__ __launch_bounds__(256) void k_tail(const float* __restrict__ pre,
        const float* __restrict__ gsum, const float* __restrict__ gsumsq,
        const float* __restrict__ g1, const float* __restrict__ beta1,
        const float* __restrict__ m2w, const float* __restrict__ m2b,
        const float* __restrict__ g2, const float* __restrict__ beta2,
        float* __restrict__ out) {
    __shared__ float xg1[100][97];   // +1 pad: kill 32-way bank conflict on row reads
    __shared__ float pre2[200];
    __shared__ float ab2[4];
    const int tid = threadIdx.x;
    if (tid < 96) {
        const float invN = 1.f / NG;
        float mean = gsum[tid] * invN;
        float var = fmaxf(gsumsq[tid] * invN - mean * mean, 0.f);
        float a = g1[tid] * rsqrtf(var + EPS);
        float bb = beta1[tid] - mean * a;
        for (int n = 0; n < NG; ++n)
            xg1[n][tid] = fmaf(a, pre[n * 96 + tid], bb);
    }
    __syncthreads();
    if (tid < 200) {
        int n = tid >> 1, cc = tid & 1;
        float acc = m2b[cc];
        const float* w = &m2w[cc * 96];
#pragma unroll 8
        for (int k = 0; k < 96; ++k) acc = fmaf(xg1[n][k], w[k], acc);
        pre2[tid] = fmaxf(acc, 0.f);
    }
    __syncthreads();
    if (tid < 2) {
        float s = 0.f, ss = 0.f;
        for (int n = 0; n < NG; ++n) { float v = pre2[n * 2 + tid]; s += v; ss = fmaf(v, v, ss); }
        const float invN = 1.f / NG;
        float mean = s * invN;
        float var = fmaxf(ss * invN - mean * mean, 0.f);
        float a = g2[tid] * rsqrtf(var + EPS);
        ab2[tid] = a;
        ab2[2 + tid] = beta2[tid] - mean * a;
    }
    __syncthreads();
    if (tid < 200) {
        int cc = tid & 1;
        out[tid] = fmaf(ab2[cc], pre2[tid], ab2[2 + cc]);
    }
}

extern "C" void kernel_launch(void* const* d_in, const int* in_sizes, int n_in,
                              void* d_out, int out_size, void* d_ws, size_t ws_size,
                              hipStream_t stream) {
    (void)in_sizes; (void)n_in; (void)out_size; (void)ws_size;
    const float* x       = (const float*)d_in[0];
    const float* ea      = (const float*)d_in[1];
    const float* c1w     = (const float*)d_in[2];
    const float* c1b     = (const float*)d_in[3];
    const float* c1g     = (const float*)d_in[4];
    const float* c1beta  = (const float*)d_in[5];
    const float* c1root  = (const float*)d_in[6];
    const float* c1bias  = (const float*)d_in[7];
    const float* c2w     = (const float*)d_in[8];
    const float* c2b     = (const float*)d_in[9];
    const float* c2g     = (const float*)d_in[10];
    const float* c2beta  = (const float*)d_in[11];
    const float* c2root  = (const float*)d_in[12];
    const float* c2bias  = (const float*)d_in[13];
    const float* lin1w   = (const float*)d_in[14];
    const float* lin1b   = (const float*)d_in[15];
    const float* lin1g   = (const float*)d_in[16];
    const float* lin1bt  = (const float*)d_in[17];
    const float* wih     = (const float*)d_in[18];
    const float* whh     = (const float*)d_in[19];
    const float* bih     = (const float*)d_in[20];
    const float* bhh     = (const float*)d_in[21];
    const float* s2sw    = (const float*)d_in[22];
    const float* s2sb    = (const float*)d_in[23];
    const float* m1w     = (const float*)d_in[24];
    const float* m1b     = (const float*)d_in[25];
    const float* m1g     = (const float*)d_in[26];
    const float* m1beta  = (const float*)d_in[27];
    const float* m2w     = (const float*)d_in[28];
    const float* m2b     = (const float*)d_in[29];
    const float* m2g     = (const float*)d_in[30];
    const float* m2beta  = (const float*)d_in[31];
    const int* src       = (const int*)d_in[32];
    const int* dst       = (const int*)d_in[33];
    const int* batch     = (const int*)d_in[34];

    float* ws = (float*)d_ws;
    float* stats1 = ws;               // 2048
    float* stats2 = ws + 2048;        // 2048
    float* linst  = ws + 4096;        // 192
    float* m1st   = ws + 4288;        // 192
    float* AB1    = ws + 4480;        // 2048
    float* AB2    = ws + 6528;        // 2048
    int*   start  = (int*)(ws + 8576);// 101 (pad to 128)
    float* x1     = ws + 8704;        // 320000
    float* x2     = x1 + 320000;      // 320000
    float* prelin = x2 + 320000;      // 960000 (BN in-place -> xc)
    float* e_ws   = prelin + 960000;  // 10000
    float* qs_g   = e_ws + 10000;     // 19200
    float* prem1  = qs_g + 19200;     // 9600

    hipMemsetAsync(ws, 0, 4480 * sizeof(float), stream);
    k_gstart<<<1, 128, 0, stream>>>(batch, start);

    // ---- conv1
    k_stats<<<640, 256, 0, stream>>>(ea, c1w, c1b, stats1, stats1 + 1024);
    k_finalize<<<4, 256, 0, stream>>>(stats1, stats1 + 1024, c1g, c1beta, AB1, AB1 + 1024, 1024, 1.f / NE);
    k_root<<<1250, 256, 0, stream>>>(x, c1root, c1bias, x1);
    k_conv<<<1024, 256, 0, stream>>>(x, ea, src, dst, c1w, c1b, AB1, AB1 + 1024, x1);

    // ---- conv2
    k_stats<<<640, 256, 0, stream>>>(ea, c2w, c2b, stats2, stats2 + 1024);
    k_finalize<<<4, 256, 0, stream>>>(stats2, stats2 + 1024, c2g, c2beta, AB2, AB2 + 1024, 1024, 1.f / NE);
    k_root<<<1250, 256, 0, stream>>>(x1, c2root, c2bias, x2);
    k_conv<<<1024, 256, 0, stream>>>(x1, ea, src, dst, c2w, c2b, AB2, AB2 + 1024, x2);

    // ---- lin1 (Linear+ReLU+BN)
    k_lin1a<<<250, 384, 0, stream>>>(x1, x2, lin1w, lin1b, prelin, linst, linst + 96);
    k_lin1b<<<250, 384, 0, stream>>>(linst, linst + 96, lin1g, lin1bt, prelin, prelin);

    // ---- Set2Set
    k_s2s<<<100, 256, 0, stream>>>(prelin, start, wih, whh, bih, bhh, qs_g, e_ws);

    // ---- tail MLPs
    k_xg<<<100, 128, 0, stream>>>(qs_g, s2sw, s2sb, m1w, m1b, prem1, m1st, m1st + 96);
    k_tail<<<1, 256, 0, stream>>>(prem1, m1st, m1st + 96, m1g, m1beta,
                                  m2w, m2b, m2g, m2beta, (float*)d_out);
}

// Round 2
// 393.536 us; speedup vs baseline: 1.1126x; 1.1126x over previous
//
#include <hip/hip_runtime.h>
#include <math.h>

#define NN 10000       // N_NODES
#define NE 160000      // N_EDGES
#define NG 100         // N_GRAPHS
#define DD 32
#define QQ 96
#define EPS 1e-5f

// ---------------------------------------------------------------- graph ranges
__global__ void k_gstart(const int* __restrict__ batch, int* __restrict__ start) {
    int b = threadIdx.x;
    if (b > NG) return;
    int lo = 0, hi = NN;
    while (lo < hi) { int mid = (lo + hi) >> 1; if (batch[mid] < b) lo = mid + 1; else hi = mid; }
    start[b] = lo;
}

// ------------------------------------------------- edge-MLP column stats (BN)
// 256-edge chunks; LDS rows padded to 8 floats -> b128+b64 reads (2 DS ops/edge)
__global__ __launch_bounds__(256) void k_stats(const float* __restrict__ ea,
        const float* __restrict__ nw, const float* __restrict__ nb,
        float* __restrict__ csum, float* __restrict__ csumsq) {
    __shared__ float lds_ea[256][8];
    const int tid = threadIdx.x;
    const int j0 = tid * 4;
    float w[4][6], bb[4];
#pragma unroll
    for (int c = 0; c < 4; ++c) {
#pragma unroll
        for (int k = 0; k < 6; ++k) w[c][k] = nw[(j0 + c) * 6 + k];
        bb[c] = nb[j0 + c];
    }
    float s[4] = {0, 0, 0, 0}, ss[4] = {0, 0, 0, 0};
    const int base = blockIdx.x * 256 * 6;
#pragma unroll
    for (int r = 0; r < 6; ++r) {
        int idx = tid + 256 * r;
        int el = idx / 6;
        int k = idx - el * 6;
        lds_ea[el][k] = ea[base + idx];
    }
    __syncthreads();
#pragma unroll 4
    for (int el = 0; el < 256; ++el) {
        float4 v0 = *reinterpret_cast<const float4*>(&lds_ea[el][0]);
        float2 v1 = *reinterpret_cast<const float2*>(&lds_ea[el][4]);
#pragma unroll
        for (int c = 0; c < 4; ++c) {
            float y = bb[c];
            y = fmaf(v0.x, w[c][0], y); y = fmaf(v0.y, w[c][1], y); y = fmaf(v0.z, w[c][2], y);
            y = fmaf(v0.w, w[c][3], y); y = fmaf(v1.x, w[c][4], y); y = fmaf(v1.y, w[c][5], y);
            float r = fmaxf(y, 0.f);
            s[c] += r; ss[c] = fmaf(r, r, ss[c]);
        }
    }
#pragma unroll
    for (int c = 0; c < 4; ++c) {
        atomicAdd(&csum[j0 + c], s[c]);
        atomicAdd(&csumsq[j0 + c], ss[c]);
    }
}

// ------------------------------------------------------- BN -> affine (A, B)
__global__ void k_finalize(const float* __restrict__ csum, const float* __restrict__ csumsq,
        const float* __restrict__ g, const float* __restrict__ beta,
        float* __restrict__ A, float* __restrict__ B, int n, float invE) {
    int j = blockIdx.x * blockDim.x + threadIdx.x;
    if (j >= n) return;
    float mean = csum[j] * invE;
    float var = fmaxf(csumsq[j] * invE - mean * mean, 0.f);
    float inv = rsqrtf(var + EPS);
    float a = g[j] * inv;
    A[j] = a;
    B[j] = beta[j] - mean * a;
}

// -------------------------------------------- out[n,o] = bias[o] + x[n]@root
__global__ __launch_bounds__(256) void k_root(const float* __restrict__ x,
        const float* __restrict__ root, const float* __restrict__ bias,
        float* __restrict__ out) {
    __shared__ float rlds[1024];
    const int tid = threadIdx.x;
#pragma unroll
    for (int r = 0; r < 4; ++r) rlds[tid + 256 * r] = root[tid + 256 * r];
    __syncthreads();
    const int o = tid & 31;
    const int gg = tid >> 5;
    const int n = blockIdx.x * 8 + gg;
    if (n >= NN) return;
    const int half = tid & 32;
    float xs = x[n * 32 + o];
    float acc = bias[o];
#pragma unroll
    for (int i = 0; i < 32; ++i) {
        float xi = __shfl(xs, half | i);
        acc = fmaf(xi, rlds[i * 32 + o], acc);
    }
    out[n * 32 + o] = acc;
}

// --------------------- fused edge-MLP recompute + matvec + scatter-add (NNConv)
__global__ __launch_bounds__(256) void k_conv(const float* __restrict__ xin,
        const float* __restrict__ ea, const int* __restrict__ src, const int* __restrict__ dst,
        const float* __restrict__ nw, const float* __restrict__ nb,
        const float* __restrict__ A, const float* __restrict__ B,
        float* __restrict__ agg) {
    __shared__ float wT[8][1024];   // w0..w5, bias, A  (transposed: stride-1 -> no bank conflict)
    __shared__ float BB[1024];
    __shared__ float ea_s[64 * 6];
    __shared__ int src_s[64];
    __shared__ int dst_s[64];
    const int tid = threadIdx.x;
    for (int idx = tid; idx < 9216; idx += 256) {
        int k = idx >> 10, j = idx & 1023;
        float v;
        if (k < 6) v = nw[j * 6 + k];
        else if (k == 6) v = nb[j];
        else if (k == 7) v = A[j];
        else v = B[j];
        if (k < 8) wT[k][j] = v; else BB[j] = v;
    }
    const int o = tid & 31;
    const int hw = tid >> 5;       // 0..7 half-waves
    const int half = tid & 32;
    const int nchunk = NE / 64;
    for (int ch = blockIdx.x; ch < nchunk; ch += gridDim.x) {
        const int base = ch * 64;
        __syncthreads();  // protect LDS (also covers initial weight load)
        if (tid < 64) { src_s[tid] = src[base + tid]; dst_s[tid] = dst[base + tid]; }
        for (int idx = tid; idx < 384; idx += 256) ea_s[idx] = ea[base * 6 + idx];
        __syncthreads();
        float ear[8][6], xs[8], msg[8];
#pragma unroll
        for (int m = 0; m < 8; ++m) {
            const float* p = &ea_s[(hw * 8 + m) * 6];
#pragma unroll
            for (int k = 0; k < 6; ++k) ear[m][k] = p[k];
            xs[m] = xin[src_s[hw * 8 + m] * 32 + o];
            msg[m] = 0.f;
        }
#pragma unroll 4
        for (int i = 0; i < 32; ++i) {
            const int j = i * 32 + o;
            float w0 = wT[0][j], w1 = wT[1][j], w2 = wT[2][j];
            float w3 = wT[3][j], w4 = wT[4][j], w5 = wT[5][j];
            float bb = wT[6][j], aa = wT[7][j], bv = BB[j];
            const int sl = half | i;
#pragma unroll
            for (int m = 0; m < 8; ++m) {
                float xi = __shfl(xs[m], sl);
                float y = bb;
                y = fmaf(ear[m][0], w0, y); y = fmaf(ear[m][1], w1, y);
                y = fmaf(ear[m][2], w2, y); y = fmaf(ear[m][3], w3, y);
                y = fmaf(ear[m][4], w4, y); y = fmaf(ear[m][5], w5, y);
                float r = fmaxf(y, 0.f);
                float t = fmaf(aa, r, bv);
                msg[m] = fmaf(xi, t, msg[m]);
            }
        }
#pragma unroll
        for (int m = 0; m < 8; ++m)
            atomicAdd(&agg[dst_s[hw * 8 + m] * 32 + o], msg[m]);
    }
}

// ---------------------------------------- lin1: relu(cat(x1,x2)@W^T+b) + stats
__global__ __launch_bounds__(384) void k_lin1a(const float* __restrict__ x1,
        const float* __restrict__ x2, const float* __restrict__ lw, const float* __restrict__ lb,
        float* __restrict__ pre, float* __restrict__ gsum, float* __restrict__ gsumsq) {
    __shared__ float cat[4][64];
    __shared__ float sh_s[96], sh_ss[96];
    const int tid = threadIdx.x;
    const int np = tid / 96;   // 0..3
    const int q = tid - np * 96;
    float w[64];
#pragma unroll
    for (int k = 0; k < 64; ++k) w[k] = lw[q * 64 + k];
    const float bq = lb[q];
    float s = 0.f, ss = 0.f;
    for (int nb = blockIdx.x * 4; nb < NN; nb += gridDim.x * 4) {
        __syncthreads();
        if (tid < 256) {
            int n2 = tid >> 6, k = tid & 63;
            cat[n2][k] = (k < 32) ? x1[(nb + n2) * 32 + k] : x2[(nb + n2) * 32 + (k - 32)];
        }
        __syncthreads();
        float v = bq;
#pragma unroll
        for (int k = 0; k < 64; ++k) v = fmaf(cat[np][k], w[k], v);
        float r = fmaxf(v, 0.f);
        pre[(nb + np) * 96 + q] = r;
        s += r; ss = fmaf(r, r, ss);
    }
    __syncthreads();
    if (tid < 96) { sh_s[tid] = 0.f; sh_ss[tid] = 0.f; }
    __syncthreads();
    atomicAdd(&sh_s[q], s);
    atomicAdd(&sh_ss[q], ss);
    __syncthreads();
    if (tid < 96) {
        atomicAdd(&gsum[tid], sh_s[tid]);
        atomicAdd(&gsumsq[tid], sh_ss[tid]);
    }
}

__global__ __launch_bounds__(384) void k_lin1b(const float* __restrict__ gsum,
        const float* __restrict__ gsumsq, const float* __restrict__ g, const float* __restrict__ beta,
        const float* __restrict__ pre, float* __restrict__ xc) {
    const int tid = threadIdx.x;
    const int np = tid / 96;
    const int q = tid - np * 96;
    const float invN = 1.f / NN;
    float mean = gsum[q] * invN;
    float var = fmaxf(gsumsq[q] * invN - mean * mean, 0.f);
    float a = g[q] * rsqrtf(var + EPS);
    float b = beta[q] - mean * a;
    for (int nb = blockIdx.x * 4; nb < NN; nb += gridDim.x * 4) {
        int n = nb + np;
        xc[n * 96 + q] = fmaf(a, pre[n * 96 + q], b);
    }
}

// ------------------------------------------------- Set2Set: whole loop per graph
// 512 threads: node-parallel logits/exp, 5x96 node-group weighted sum
__global__ __launch_bounds__(512) void k_s2s(const float* __restrict__ xc,
        const int* __restrict__ start,
        const float* __restrict__ w_ih, const float* __restrict__ w_hh,
        const float* __restrict__ b_ih, const float* __restrict__ b_hh,
        float* __restrict__ qs_g, float* __restrict__ e_ws) {
    __shared__ float qs[192], h[96], c[96], gates[384];
    __shared__ float redm[8], reds[8];
    __shared__ float racc_s[5][96];
    __shared__ float sh_scal[2];   // [0]=emax, [1]=1/asum
    const int tid = threadIdx.x;
    const int wid = tid >> 6, lane = tid & 63;
    const int b = blockIdx.x;
    const int s = start[b], t = start[b + 1];
    if (tid < 192) qs[tid] = 0.f;
    if (tid < 96) { h[tid] = 0.f; c[tid] = 0.f; }
    __syncthreads();
    for (int step = 0; step < 3; ++step) {
        // gates = qs@w_ih^T + b_ih + h@w_hh^T + b_hh
        if (tid < 384) {
            float acc = b_ih[tid] + b_hh[tid];
            const float* wi = &w_ih[tid * 192];
#pragma unroll 8
            for (int k = 0; k < 192; ++k) acc = fmaf(qs[k], wi[k], acc);
            const float* wh = &w_hh[tid * 96];
#pragma unroll 8
            for (int k = 0; k < 96; ++k) acc = fmaf(h[k], wh[k], acc);
            gates[tid] = acc;
        }
        __syncthreads();
        if (tid < 96) {
            float ig = 1.f / (1.f + __expf(-gates[tid]));
            float fg = 1.f / (1.f + __expf(-gates[96 + tid]));
            float gg = tanhf(gates[192 + tid]);
            float og = 1.f / (1.f + __expf(-gates[288 + tid]));
            float cn = fg * c[tid] + ig * gg;
            c[tid] = cn;
            h[tid] = og * tanhf(cn);
        }
        __syncthreads();
        // attention logits, node-parallel
        float pmax = -INFINITY;
        for (int n = s + tid; n < t; n += 512) {
            const float* xr = &xc[n * 96];
            float acc = 0.f;
#pragma unroll 8
            for (int k = 0; k < 96; ++k) acc = fmaf(xr[k], h[k], acc);
            e_ws[n] = acc;
            pmax = fmaxf(pmax, acc);
        }
#pragma unroll
        for (int off = 32; off > 0; off >>= 1) pmax = fmaxf(pmax, __shfl_down(pmax, off));
        if (lane == 0) redm[wid] = pmax;
        __syncthreads();
        if (tid == 0) {
            float m = redm[0];
#pragma unroll
            for (int i = 1; i < 8; ++i) m = fmaxf(m, redm[i]);
            if (!isfinite(m)) m = 0.f;
            sh_scal[0] = m;
        }
        __syncthreads();
        const float emax = sh_scal[0];
        // p = exp(e-emax), node-parallel; accumulate asum
        float pa = 0.f;
        for (int n = s + tid; n < t; n += 512) {
            float a = __expf(e_ws[n] - emax);
            e_ws[n] = a;
            pa += a;
        }
#pragma unroll
        for (int off = 32; off > 0; off >>= 1) pa += __shfl_down(pa, off);
        if (lane == 0) reds[wid] = pa;
        __syncthreads();
        if (tid == 0) {
            float a2 = 0.f;
#pragma unroll
            for (int i = 0; i < 8; ++i) a2 += reds[i];
            sh_scal[1] = (a2 > 0.f) ? 1.f / a2 : 0.f;
        }
        __syncthreads();   // also makes e_ws (=p) visible block-wide
        // weighted sum r[q] = sum_n p[n]*xc[n][q], 5 node-groups x 96 dims
        const int g = tid / 96, q = tid - g * 96;
        if (tid < 480) {
            float racc = 0.f;
            for (int n = s + g; n < t; n += 5)
                racc = fmaf(e_ws[n], xc[n * 96 + q], racc);
            racc_s[g][q] = racc;
        }
        __syncthreads();
        if (tid < 96) {
            float r = (racc_s[0][tid] + racc_s[1][tid] + racc_s[2][tid]
                     + racc_s[3][tid] + racc_s[4][tid]) * sh_scal[1];
            qs[tid] = h[tid];
            qs[96 + tid] = r;
        }
        __syncthreads();
    }
    if (tid < 192) qs_g[b * 192 + tid] = qs[tid];
}

// -------------------------------- xg = qs@s2s_w^T+b ; pre_m1 = relu(xg@m1^T+b)
__global__ __launch_bounds__(128) void k_xg(const float* __restrict__ qs_g,
        const float* __restrict__ sw, const float* __restrict__ sb,
        const float* __restrict__ m1w, const float* __restrict__ m1b,
        float* __restrict__ pre, float* __restrict__ gsum, float* __restrict__ gsumsq) {
    __shared__ float xg0[96];
    const int tid = threadIdx.x;
    const int b = blockIdx.x;
    if (tid < 96) {
        const float* q = &qs_g[b * 192];
        float acc = sb[tid];
        const float* w = &sw[tid * 192];
#pragma unroll 8
        for (int k = 0; k < 192; ++k) acc = fmaf(q[k], w[k], acc);
        xg0[tid] = acc;
    }
    __syncthreads();
    if (tid < 96) {
        float acc = m1b[tid];
        const float* w = &m1w[tid * 96];
#pragma unroll 8
        for (int k = 0; k < 96; ++k) acc = fmaf(xg0[k], w[k], acc);
        float r = fmaxf(acc, 0.f);
        pre[b * 96 + tid] = r;
        atomicAdd(&gsum[tid], r);
        atomicAdd(&gsumsq[tid], r * r);
    }
}

// ----------------------------------------- tail: BN(m1) -> m2 linear+relu+BN
__global__ __launch_bounds__(256) void k_tail(const float* __restrict__ pre,
        const float* __restrict__ gsum, const float* __restrict__ gsumsq,
        const float* __restrict__ g1, const float* __restrict__ beta1,
        const float* __restrict__ m2w, const float* __restrict__ m2b,
        const float* __restrict__ g2, const float* __restrict__ beta2,
        float* __restrict__ out) {
    __shared__ float xg1[100][97];   // +1 pad: kill 32-way bank conflict on row reads
    __shared__ float pre2[200];
    __shared__ float ab2[4];
    const int tid = threadIdx.x;
    if (tid < 96) {
        const float invN = 1.f / NG;
        float mean = gsum[tid] * invN;
        float var = fmaxf(gsumsq[tid] * invN - mean * mean, 0.f);
        float a = g1[tid] * rsqrtf(var + EPS);
        float bb = beta1[tid] - mean * a;
        for (int n = 0; n < NG; ++n)
            xg1[n][tid] = fmaf(a, pre[n * 96 + tid], bb);
    }
    __syncthreads();
    if (tid < 200) {
        int n = tid >> 1, cc = tid & 1;
        float acc = m2b[cc];
        const float* w = &m2w[cc * 96];
#pragma unroll 8
        for (int k = 0; k < 96; ++k) acc = fmaf(xg1[n][k], w[k], acc);
        pre2[tid] = fmaxf(acc, 0.f);
    }
    __syncthreads();
    if (tid < 2) {
        float s = 0.f, ss = 0.f;
        for (int n = 0; n < NG; ++n) { float v = pre2[n * 2 + tid]; s += v; ss = fmaf(v, v, ss); }
        const float invN = 1.f / NG;
        float mean = s * invN;
        float var = fmaxf(ss * invN - mean * mean, 0.f);
        float a = g2[tid] * rsqrtf(var + EPS);
        ab2[tid] = a;
        ab2[2 + tid] = beta2[tid] - mean * a;
    }
    __syncthreads();
    if (tid < 200) {
        int cc = tid & 1;
        out[tid] = fmaf(ab2[cc], pre2[tid], ab2[2 + cc]);
    }
}

extern "C" void kernel_launch(void* const* d_in, const int* in_sizes, int n_in,
                              void* d_out, int out_size, void* d_ws, size_t ws_size,
                              hipStream_t stream) {
    (void)in_sizes; (void)n_in; (void)out_size; (void)ws_size;
    const float* x       = (const float*)d_in[0];
    const float* ea      = (const float*)d_in[1];
    const float* c1w     = (const float*)d_in[2];
    const float* c1b     = (const float*)d_in[3];
    const float* c1g     = (const float*)d_in[4];
    const float* c1beta  = (const float*)d_in[5];
    const float* c1root  = (const float*)d_in[6];
    const float* c1bias  = (const float*)d_in[7];
    const float* c2w     = (const float*)d_in[8];
    const float* c2b     = (const float*)d_in[9];
    const float* c2g     = (const float*)d_in[10];
    const float* c2beta  = (const float*)d_in[11];
    const float* c2root  = (const float*)d_in[12];
    const float* c2bias  = (const float*)d_in[13];
    const float* lin1w   = (const float*)d_in[14];
    const float* lin1b   = (const float*)d_in[15];
    const float* lin1g   = (const float*)d_in[16];
    const float* lin1bt  = (const float*)d_in[17];
    const float* wih     = (const float*)d_in[18];
    const float* whh     = (const float*)d_in[19];
    const float* bih     = (const float*)d_in[20];
    const float* bhh     = (const float*)d_in[21];
    const float* s2sw    = (const float*)d_in[22];
    const float* s2sb    = (const float*)d_in[23];
    const float* m1w     = (const float*)d_in[24];
    const float* m1b     = (const float*)d_in[25];
    const float* m1g     = (const float*)d_in[26];
    const float* m1beta  = (const float*)d_in[27];
    const float* m2w     = (const float*)d_in[28];
    const float* m2b     = (const float*)d_in[29];
    const float* m2g     = (const float*)d_in[30];
    const float* m2beta  = (const float*)d_in[31];
    const int* src       = (const int*)d_in[32];
    const int* dst       = (const int*)d_in[33];
    const int* batch     = (const int*)d_in[34];

    float* ws = (float*)d_ws;
    float* stats1 = ws;               // 2048
    float* stats2 = ws + 2048;        // 2048
    float* linst  = ws + 4096;        // 192
    float* m1st   = ws + 4288;        // 192
    float* AB1    = ws + 4480;        // 2048
    float* AB2    = ws + 6528;        // 2048
    int*   start  = (int*)(ws + 8576);// 101 (pad to 128)
    float* x1     = ws + 8704;        // 320000
    float* x2     = x1 + 320000;      // 320000
    float* prelin = x2 + 320000;      // 960000 (BN in-place -> xc)
    float* e_ws   = prelin + 960000;  // 10000
    float* qs_g   = e_ws + 10000;     // 19200
    float* prem1  = qs_g + 19200;     // 9600

    hipMemsetAsync(ws, 0, 4480 * sizeof(float), stream);
    k_gstart<<<1, 128, 0, stream>>>(batch, start);

    // ---- conv1
    k_stats<<<625, 256, 0, stream>>>(ea, c1w, c1b, stats1, stats1 + 1024);
    k_finalize<<<4, 256, 0, stream>>>(stats1, stats1 + 1024, c1g, c1beta, AB1, AB1 + 1024, 1024, 1.f / NE);
    k_root<<<1250, 256, 0, stream>>>(x, c1root, c1bias, x1);
    k_conv<<<1250, 256, 0, stream>>>(x, ea, src, dst, c1w, c1b, AB1, AB1 + 1024, x1);

    // ---- conv2
    k_stats<<<625, 256, 0, stream>>>(ea, c2w, c2b, stats2, stats2 + 1024);
    k_finalize<<<4, 256, 0, stream>>>(stats2, stats2 + 1024, c2g, c2beta, AB2, AB2 + 1024, 1024, 1.f / NE);
    k_root<<<1250, 256, 0, stream>>>(x1, c2root, c2bias, x2);
    k_conv<<<1250, 256, 0, stream>>>(x1, ea, src, dst, c2w, c2b, AB2, AB2 + 1024, x2);

    // ---- lin1 (Linear+ReLU+BN)
    k_lin1a<<<250, 384, 0, stream>>>(x1, x2, lin1w, lin1b, prelin, linst, linst + 96);
    k_lin1b<<<250, 384, 0, stream>>>(linst, linst + 96, lin1g, lin1bt, prelin, prelin);

    // ---- Set2Set
    k_s2s<<<100, 512, 0, stream>>>(prelin, start, wih, whh, bih, bhh, qs_g, e_ws);

    // ---- tail MLPs
    k_xg<<<100, 128, 0, stream>>>(qs_g, s2sw, s2sb, m1w, m1b, prem1, m1st, m1st + 96);
    k_tail<<<1, 256, 0, stream>>>(prem1, m1st, m1st + 96, m1g, m1beta,
                                  m2w, m2b, m2g, m2beta, (float*)d_out);
}